// Round 10
// baseline (537.137 us; speedup 1.0000x reference)
//
#include <hip/hip_runtime.h>

typedef short  short8  __attribute__((ext_vector_type(8)));
typedef float  floatx4 __attribute__((ext_vector_type(4)));

#define TT 512
#define DD 32
#define HH 128
#define AA 10
#define LOG2E 1.44269504088896340736f

__device__ __forceinline__ unsigned f2bf(float f) {
    unsigned u = __builtin_bit_cast(unsigned, f);
    return (u + 0x7fffu + ((u >> 16) & 1u)) >> 16;   // RNE f32 -> bf16
}

__device__ __forceinline__ short8 cvt8(floatx4 a, floatx4 b) {
    short8 r;
    r[0] = (short)f2bf(a[0]); r[1] = (short)f2bf(a[1]);
    r[2] = (short)f2bf(a[2]); r[3] = (short)f2bf(a[3]);
    r[4] = (short)f2bf(b[0]); r[5] = (short)f2bf(b[1]);
    r[6] = (short)f2bf(b[2]); r[7] = (short)f2bf(b[3]);
    return r;
}

// activations on pre-scaled gates (scale folded into weights/bias)
__device__ __forceinline__ float sig2(float a) {   // a = -x*log2e
    return __builtin_amdgcn_rcpf(1.0f + __builtin_amdgcn_exp2f(a));
}
__device__ __forceinline__ float tanh2(float a) {  // a = 2x*log2e
    return 1.0f - 2.0f * __builtin_amdgcn_rcpf(1.0f + __builtin_amdgcn_exp2f(a));
}

// lgkm-only phase barrier: x prefetch loads float across it
__device__ __forceinline__ void step_barrier() {
    asm volatile("s_waitcnt lgkmcnt(0)" ::: "memory");
    __builtin_amdgcn_s_barrier();
    asm volatile("" ::: "memory");
}

// Prepass: x (f32) -> bf16 in d_ws, same [B][T][D] layout.
__global__ __launch_bounds__(256)
void xcvt(const float* __restrict__ x, unsigned short* __restrict__ xb) {
    const long i = (long)blockIdx.x * 256 + threadIdx.x;
    floatx4 a = *(const floatx4*)(x + 8 * i);
    floatx4 b = *(const floatx4*)(x + 8 * i + 4);
    *(short8*)(xb + 8 * i) = cvt8(a, b);
}

// Dual-recurrence phase pipeline.  One block = 8 batch rows as two
// independent groups G0 (rows 0-3) and G1 (rows 4-7); weights/bias regs are
// SHARED.  Each phase: {ds_read + 20 MFMA for group A} overlapped with
// {EW + h-write for group B} -- the EW depends only on the PREVIOUS phase's
// accs, so it is independent work that fills the MFMA/ds latency inside the
// same wave (sched_barrier pins it between x-MFMAs and h-MFMAs).
// 256 blocks; blocks 128-255 mirror (blockIdx&127) and skip global writes.
// h layout per (group,parity) buffer: addr(b,j) = b*256 + ((2j+32b)&255).
template<int USEWS>
__global__ __launch_bounds__(512, 2)
void lstm_fused(const float* __restrict__ x,    const unsigned short* __restrict__ xbf,
                const float* __restrict__ W_ih, const float* __restrict__ W_hh,
                const float* __restrict__ b_ih, const float* __restrict__ b_hh,
                const float* __restrict__ fc_w, const float* __restrict__ fc_b,
                float* __restrict__ out)
{
    __shared__ unsigned short h_lds[4][4 * HH];   // [g*2+par][512] bf16 = 4 KiB
    __shared__ float hq[8][HH + 4];

    const int tid  = threadIdx.x;
    const int lane = tid & 63;
    const int w    = tid >> 6;
    const int l15  = lane & 15;
    const int lgrp = lane >> 4;     // k-group 0..3
    const int bloc = l15 & 3;       // batch row (within group) of this lane

    const int  blk = blockIdx.x & 127;
    const long bg0 = (long)blk * 8 + bloc;   // G0 batch row
    const long bg1 = bg0 + 4;                // G1 batch row

    // ---- resident A-fragments (bf16, gate-scaled) + bias C-operands ----
    short8  afr[4][5];
    floatx4 biasv[4];
    #pragma unroll
    for (int tg = 0; tg < 4; ++tg) {
        const float sc = (tg == 2) ? (2.0f * LOG2E) : (-LOG2E);
        const int m  = w + 8 * tg;
        const int ga = 16 * m + l15;
        #pragma unroll
        for (int s = 0; s < 4; ++s) {
            const float* p = W_hh + ga * HH + 32 * s + 8 * lgrp;
            afr[tg][s] = cvt8(*(const floatx4*)p * sc, *(const floatx4*)(p + 4) * sc);
        }
        {
            const float* p = W_ih + ga * DD + 8 * lgrp;
            afr[tg][4] = cvt8(*(const floatx4*)p * sc, *(const floatx4*)(p + 4) * sc);
        }
        #pragma unroll
        for (int r = 0; r < 4; ++r) {
            const int gd = 16 * m + 4 * lgrp + r;
            biasv[tg][r] = (b_ih[gd] + b_hh[gd]) * sc;
        }
    }

    // zero all 4 h buffers: 1024 dwords, 512 threads
    ((unsigned*)h_lds)[tid]       = 0u;
    ((unsigned*)h_lds)[tid + 512] = 0u;
    __syncthreads();

    // packed-lane mapping (same as R6): lane owns value (bp, jp) per group
    const int rs  = l15 >> 2;
    const bool sb0 = (rs & 1) != 0;
    const bool sb1 = (rs & 2) != 0;
    const int bp  = bloc;
    const int jp  = 16 * w + 4 * lgrp + rs;

    // rotation-swizzle offsets (relative to a 1 KiB group/parity buffer)
    const int rdR0 = bloc * 256 + ((  0 + 16 * lgrp + 32 * bloc) & 255);
    const int rdR1 = bloc * 256 + (( 64 + 16 * lgrp + 32 * bloc) & 255);
    const int rdR2 = bloc * 256 + ((128 + 16 * lgrp + 32 * bloc) & 255);
    const int rdR3 = bloc * 256 + ((192 + 16 * lgrp + 32 * bloc) & 255);
    const int wrR  = bp * 256 + ((2 * jp + 32 * bp) & 255);

    // x prefetch state, one stream per group
    short8  xf0, xf1;
    floatx4 xa0, xb0, xa1, xb1;
    if constexpr (USEWS) {
        xf0 = *(const short8*)(xbf + (bg0 * TT) * DD + 8 * lgrp);
        xf1 = *(const short8*)(xbf + (bg1 * TT) * DD + 8 * lgrp);
    } else {
        xa0 = *(const floatx4*)(x + (bg0 * TT) * DD + 8 * lgrp);
        xb0 = *(const floatx4*)(x + (bg0 * TT) * DD + 8 * lgrp + 4);
        xa1 = *(const floatx4*)(x + (bg1 * TT) * DD + 8 * lgrp);
        xb1 = *(const floatx4*)(x + (bg1 * TT) * DD + 8 * lgrp + 4);
    }

    floatx4 acc0[4], acc1[4];
    float cv0 = 0.f, hv0 = 0.f, cv1 = 0.f, hv1 = 0.f;
    char* lb = (char*)h_lds;

    // One phase: MFMA group C (acc accC, x stream xfC/xaC..), reading h from
    // byte base RDB; EW group E (accE -> cvE,hvE), writing h to byte base WRB.
    auto PHASE = [&](floatx4 (&accC)[4], short8& xfC, floatx4& xaC, floatx4& xbC,
                     const long bgC, int tC, int RDB,
                     floatx4 (&accE)[4], float& cvE, float& hvE, int WRB,
                     bool DOEW) {
        // 1. issue h-frag reads for C (latency hidden under EW below)
        short8 hb0 = *(const short8*)(lb + RDB + rdR0);
        short8 hb1 = *(const short8*)(lb + RDB + rdR1);
        short8 hb2 = *(const short8*)(lb + RDB + rdR2);
        short8 hb3 = *(const short8*)(lb + RDB + rdR3);

        // 2. consume x, issue next prefetch (floats across the barrier)
        short8 xc;
        const int tn = (tC + 1 < TT) ? (tC + 1) : (TT - 1);
        if constexpr (USEWS) {
            xc = xfC;
            xfC = *(const short8*)(xbf + (bgC * TT + tn) * DD + 8 * lgrp);
        } else {
            xc = cvt8(xaC, xbC);
            const float* xp = x + (bgC * TT + tn) * DD + 8 * lgrp;
            xaC = *(const floatx4*)(xp);
            xbC = *(const floatx4*)(xp + 4);
        }

        // 3. x-MFMAs (no LDS dependency)
        #pragma unroll
        for (int tg = 0; tg < 4; ++tg)
            accC[tg] = __builtin_amdgcn_mfma_f32_16x16x32_bf16(afr[tg][4], xc, biasv[tg], 0, 0, 0);

        // 4. EW for group E (independent of this phase's MFMAs/reads)
        if (DOEW) {
            float g4[4];
            #pragma unroll
            for (int tg = 0; tg < 4; ++tg) {
                const float v01 = sb0 ? accE[tg][1] : accE[tg][0];
                const float v23 = sb0 ? accE[tg][3] : accE[tg][2];
                g4[tg] = sb1 ? v23 : v01;
            }
            const float iv = sig2(g4[0]);
            const float fv = sig2(g4[1]);
            const float gv = tanh2(g4[2]);
            const float ov = sig2(g4[3]);
            cvE = fv * cvE + iv * gv;
            hvE = ov * tanh2(cvE * (2.0f * LOG2E));
            unsigned hp;
            asm("v_cvt_pk_bf16_f32 %0, %1, %2" : "=v"(hp) : "v"(hvE), "v"(hvE));
            *(unsigned short*)(lb + WRB + wrR) = (unsigned short)hp;
        }

        // pin: EW stays above, h-MFMAs below
        __builtin_amdgcn_sched_barrier(0);

        // 5. h-MFMAs for C
        #pragma unroll
        for (int tg = 0; tg < 4; ++tg)
            accC[tg] = __builtin_amdgcn_mfma_f32_16x16x32_bf16(afr[tg][0], hb0, accC[tg], 0, 0, 0);
        #pragma unroll
        for (int tg = 0; tg < 4; ++tg)
            accC[tg] = __builtin_amdgcn_mfma_f32_16x16x32_bf16(afr[tg][1], hb1, accC[tg], 0, 0, 0);
        #pragma unroll
        for (int tg = 0; tg < 4; ++tg)
            accC[tg] = __builtin_amdgcn_mfma_f32_16x16x32_bf16(afr[tg][2], hb2, accC[tg], 0, 0, 0);
        #pragma unroll
        for (int tg = 0; tg < 4; ++tg)
            accC[tg] = __builtin_amdgcn_mfma_f32_16x16x32_bf16(afr[tg][3], hb3, accC[tg], 0, 0, 0);

        step_barrier();
    };

    // byte bases: group g, parity p -> (g*2+p)*1024
    // prologue PhA(0): MFMA G0(0) reading G0 par1 (zeroed); no EW
    PHASE(acc0, xf0, xa0, xb0, bg0, 0, 1 * 1024, acc1, cv1, hv1, 0, false);

    #pragma unroll 1
    for (int t = 0; t < TT; t += 2) {
        // PhB(t):   MFMA G1(t)   read G1 par1 (3072); EW G0(t)   write G0 par0 (0)
        PHASE(acc1, xf1, xa1, xb1, bg1, t,     3 * 1024, acc0, cv0, hv0, 0 * 1024, true);
        // PhA(t+1): MFMA G0(t+1) read G0 par0 (0);    EW G1(t)   write G1 par0 (2048)
        PHASE(acc0, xf0, xa0, xb0, bg0, t + 1, 0 * 1024, acc1, cv1, hv1, 2 * 1024, true);
        // PhB(t+1): MFMA G1(t+1) read G1 par0 (2048); EW G0(t+1) write G0 par1 (1024)
        PHASE(acc1, xf1, xa1, xb1, bg1, t + 1, 2 * 1024, acc0, cv0, hv0, 1 * 1024, true);
        // PhA(t+2): MFMA G0(t+2) read G0 par1 (1024); EW G1(t+1) write G1 par1 (3072)
        PHASE(acc0, xf0, xa0, xb0, bg0, t + 2, 1 * 1024, acc1, cv1, hv1, 3 * 1024, true);
    }
    // loop end: EW done through G0(511) (PhB(511)) and G1(511) (PhA(512)).

    // ---- epilogue: h_n, c_n, q = h @ fc_w^T + fc_b (real blocks only) ----
    if (blockIdx.x < 128) {
        const long b0 = (long)blk * 8 + bp;
        const long b1 = b0 + 4;
        out[10240 + b0 * HH + jp]          = hv0;   // h_n G0
        out[10240 + 131072 + b0 * HH + jp] = cv0;   // c_n G0
        out[10240 + b1 * HH + jp]          = hv1;   // h_n G1
        out[10240 + 131072 + b1 * HH + jp] = cv1;   // c_n G1
    }
    hq[bp][jp]     = hv0;
    hq[bp + 4][jp] = hv1;
    __syncthreads();
    if (blockIdx.x < 128 && tid < 8 * AA) {
        const int b = tid / AA, a = tid - AA * b;
        float s = fc_b[a];
        const float* fw = fc_w + a * HH;
        const float* hr = &hq[b][0];
        #pragma unroll 8
        for (int j = 0; j < HH; ++j) s = fmaf(hr[j], fw[j], s);
        out[((long)blk * 8 + b) * AA + a] = s;
    }
}

extern "C" void kernel_launch(void* const* d_in, const int* in_sizes, int n_in,
                              void* d_out, int out_size, void* d_ws, size_t ws_size,
                              hipStream_t stream) {
    const float* x    = (const float*)d_in[0];
    const float* W_ih = (const float*)d_in[1];
    const float* W_hh = (const float*)d_in[2];
    const float* b_ih = (const float*)d_in[3];
    const float* b_hh = (const float*)d_in[4];
    const float* fc_w = (const float*)d_in[5];
    const float* fc_b = (const float*)d_in[6];
    float* out = (float*)d_out;

    const size_t xelems = (size_t)1024 * TT * DD;       // 16.78M
    if (ws_size >= xelems * sizeof(unsigned short)) {
        unsigned short* xb = (unsigned short*)d_ws;
        xcvt<<<dim3(8192), dim3(256), 0, stream>>>(x, xb);
        lstm_fused<1><<<dim3(256), dim3(512), 0, stream>>>(
            x, xb, W_ih, W_hh, b_ih, b_hh, fc_w, fc_b, out);
    } else {
        lstm_fused<0><<<dim3(256), dim3(512), 0, stream>>>(
            x, nullptr, W_ih, W_hh, b_ih, b_hh, fc_w, fc_b, out);
    }
}

// Round 11
// 294.391 us; speedup vs baseline: 1.8246x; 1.8246x over previous
//
#include <hip/hip_runtime.h>

typedef short  short8  __attribute__((ext_vector_type(8)));
typedef float  floatx4 __attribute__((ext_vector_type(4)));

#define TT 512
#define DD 32
#define HH 128
#define AA 10
#define LOG2E 1.44269504088896340736f

__device__ __forceinline__ unsigned f2bf(float f) {
    unsigned u = __builtin_bit_cast(unsigned, f);
    return (u + 0x7fffu + ((u >> 16) & 1u)) >> 16;   // RNE f32 -> bf16
}

__device__ __forceinline__ short8 cvt8(floatx4 a, floatx4 b) {
    short8 r;
    r[0] = (short)f2bf(a[0]); r[1] = (short)f2bf(a[1]);
    r[2] = (short)f2bf(a[2]); r[3] = (short)f2bf(a[3]);
    r[4] = (short)f2bf(b[0]); r[5] = (short)f2bf(b[1]);
    r[6] = (short)f2bf(b[2]); r[7] = (short)f2bf(b[3]);
    return r;
}

// activations on pre-scaled gates (scale folded into weights/bias)
__device__ __forceinline__ float sig2(float a) {   // a = -x*log2e
    return __builtin_amdgcn_rcpf(1.0f + __builtin_amdgcn_exp2f(a));
}
__device__ __forceinline__ float tanh2(float a) {  // a = 2x*log2e
    return 1.0f - 2.0f * __builtin_amdgcn_rcpf(1.0f + __builtin_amdgcn_exp2f(a));
}

// lgkm-only step barrier: x prefetch loads float across it
__device__ __forceinline__ void step_barrier() {
    asm volatile("s_waitcnt lgkmcnt(0)" ::: "memory");
    __builtin_amdgcn_s_barrier();
    asm volatile("" ::: "memory");
}

// Prepass: x (f32) -> bf16 in d_ws, same [B][T][D] layout.
__global__ __launch_bounds__(256)
void xcvt(const float* __restrict__ x, unsigned short* __restrict__ xb) {
    const long i = (long)blockIdx.x * 256 + threadIdx.x;
    floatx4 a = *(const floatx4*)(x + 8 * i);
    floatx4 b = *(const floatx4*)(x + 8 * i + 4);
    *(short8*)(xb + 8 * i) = cvt8(a, b);
}

// One block = 4 batch rows; 256 blocks = 1 per CU.  (R6 structure.)
// NEW vs R6: cross-step x-MFMA deferral.  During step t, after the 16
// h-MFMAs, the wave issues 4 x-MFMAs building NEXT step's accumulator
// accN = bias + W_ih@x(t+1).  These are independent of EW(t)/h(t+1), so the
// matrix pipe stays fed while the VALU runs the elementwise phase -- filling
// part of the ~450-cyc pipe-idle window that made R6's step serial.
// acc/x-frag registers ping-pong via the x2 unroll (no moves).
// h layout: addr(b,j) = b*256 + ((2j+32b)&255)  (rotation swizzle, ~0 confl).
template<int USEWS>
__global__ __launch_bounds__(512, 2)
void lstm_fused(const float* __restrict__ x,    const unsigned short* __restrict__ xbf,
                const float* __restrict__ W_ih, const float* __restrict__ W_hh,
                const float* __restrict__ b_ih, const float* __restrict__ b_hh,
                const float* __restrict__ fc_w, const float* __restrict__ fc_b,
                float* __restrict__ out)
{
    __shared__ unsigned short h_lds[2][4 * HH];    // 2 KiB total, dbuf
    __shared__ float hq[4][HH + 4];

    const int tid  = threadIdx.x;
    const int lane = tid & 63;
    const int w    = tid >> 6;
    const int l15  = lane & 15;
    const int lgrp = lane >> 4;     // k-group 0..3
    const int bloc = l15 & 3;       // batch row of this lane's B-frag

    // ---- resident A-fragments (bf16, gate-scaled) + bias C-operands ----
    short8  afr[4][5];
    floatx4 biasv[4];
    #pragma unroll
    for (int tg = 0; tg < 4; ++tg) {
        const float sc = (tg == 2) ? (2.0f * LOG2E) : (-LOG2E);
        const int m  = w + 8 * tg;
        const int ga = 16 * m + l15;
        #pragma unroll
        for (int s = 0; s < 4; ++s) {
            const float* p = W_hh + ga * HH + 32 * s + 8 * lgrp;
            afr[tg][s] = cvt8(*(const floatx4*)p * sc, *(const floatx4*)(p + 4) * sc);
        }
        {
            const float* p = W_ih + ga * DD + 8 * lgrp;
            afr[tg][4] = cvt8(*(const floatx4*)p * sc, *(const floatx4*)(p + 4) * sc);
        }
        #pragma unroll
        for (int r = 0; r < 4; ++r) {
            const int gd = 16 * m + 4 * lgrp + r;
            biasv[tg][r] = (b_ih[gd] + b_hh[gd]) * sc;
        }
    }

    // zero both h buffers: exactly 512 dwords
    ((unsigned*)h_lds)[tid] = 0u;
    __syncthreads();

    // packed-lane mapping: quad element rs = l15>>2
    const int rs  = l15 >> 2;
    const bool sb0 = (rs & 1) != 0;
    const bool sb1 = (rs & 2) != 0;
    const int bp  = bloc;
    const int jp  = 16 * w + 4 * lgrp + rs;

    // hoisted LDS offsets (rotation swizzle)
    const int rb = bloc * 256;
    const int rdA0 = rb + ((  0 + 16 * lgrp + 32 * bloc) & 255);
    const int rdA1 = rb + (( 64 + 16 * lgrp + 32 * bloc) & 255);
    const int rdA2 = rb + ((128 + 16 * lgrp + 32 * bloc) & 255);
    const int rdA3 = rb + ((192 + 16 * lgrp + 32 * bloc) & 255);
    const int rdB0 = rdA0 + 1024, rdB1 = rdA1 + 1024, rdB2 = rdA2 + 1024, rdB3 = rdA3 + 1024;
    const int wrA = bp * 256 + ((2 * jp + 32 * bp) & 255);          // write buf0
    const int wrB = wrA + 1024;                                      // write buf1

    // x addressing: scalar base walks with t (uniform), lane offset invariant
    const size_t blkbase = (size_t)blockIdx.x * 4 * TT * DD;
    const int    xlane   = bloc * (TT * DD) + 8 * lgrp;    // elements
    const unsigned short* xsb = xbf + blkbase;             // USEWS base
    const float*          xfb = x   + blkbase;             // fallback base

    // ---- prologue: acc0 = bias + W_ih@x(0); xf1 = x(1) ----
    floatx4 acc0[4], acc1[4];
    short8  xf0, xf1;
    floatx4 xa0, xb0_, xa1, xb1_;
    if constexpr (USEWS) {
        short8 xc0 = *(const short8*)(xsb + xlane);               // x(0)
        #pragma unroll
        for (int tg = 0; tg < 4; ++tg)
            acc0[tg] = __builtin_amdgcn_mfma_f32_16x16x32_bf16(afr[tg][4], xc0, biasv[tg], 0, 0, 0);
        xf1 = *(const short8*)(xsb + DD + xlane);                 // x(1)
    } else {
        floatx4 a0 = *(const floatx4*)(xfb + xlane);
        floatx4 b0 = *(const floatx4*)(xfb + xlane + 4);
        short8 xc0 = cvt8(a0, b0);
        #pragma unroll
        for (int tg = 0; tg < 4; ++tg)
            acc0[tg] = __builtin_amdgcn_mfma_f32_16x16x32_bf16(afr[tg][4], xc0, biasv[tg], 0, 0, 0);
        xa1  = *(const floatx4*)(xfb + DD + xlane);
        xb1_ = *(const floatx4*)(xfb + DD + xlane + 4);
    }

    float cval = 0.f, hval = 0.f;
    const char* lb = (const char*)h_lds;

    // STEP(t): h-MFMAs(t) onto accP; x-MFMAs -> accN = bias + W_ih@x(t+1);
    // load x(t+2) into xL; EW(t) from accP; write h(t+1); barrier.
    auto STEP = [&](floatx4 (&accP)[4], floatx4 (&accN)[4],
                    short8& xN, floatx4& xNa, floatx4& xNb,
                    short8& xL, floatx4& xLa, floatx4& xLb,
                    int r0, int r1, int r2, int r3, int wro, int t) {
        // h fragments for this step
        short8 hb0 = *(const short8*)(lb + r0);
        short8 hb1 = *(const short8*)(lb + r1);
        short8 hb2 = *(const short8*)(lb + r2);
        short8 hb3 = *(const short8*)(lb + r3);

        // 16 h-MFMAs: 4 chains of depth 4 (accP already holds bias+x-proj)
        #pragma unroll
        for (int tg = 0; tg < 4; ++tg)
            accP[tg] = __builtin_amdgcn_mfma_f32_16x16x32_bf16(afr[tg][0], hb0, accP[tg], 0, 0, 0);
        #pragma unroll
        for (int tg = 0; tg < 4; ++tg)
            accP[tg] = __builtin_amdgcn_mfma_f32_16x16x32_bf16(afr[tg][1], hb1, accP[tg], 0, 0, 0);
        #pragma unroll
        for (int tg = 0; tg < 4; ++tg)
            accP[tg] = __builtin_amdgcn_mfma_f32_16x16x32_bf16(afr[tg][2], hb2, accP[tg], 0, 0, 0);
        #pragma unroll
        for (int tg = 0; tg < 4; ++tg)
            accP[tg] = __builtin_amdgcn_mfma_f32_16x16x32_bf16(afr[tg][3], hb3, accP[tg], 0, 0, 0);

        // 4 x-MFMAs for NEXT step (independent of EW below -> fill the pipe)
        short8 xc;
        if constexpr (USEWS) xc = xN; else xc = cvt8(xNa, xNb);
        #pragma unroll
        for (int tg = 0; tg < 4; ++tg)
            accN[tg] = __builtin_amdgcn_mfma_f32_16x16x32_bf16(afr[tg][4], xc, biasv[tg], 0, 0, 0);

        // prefetch x(t+2) (uniform scalar base + invariant lane offset)
        const int tn = (t + 2 < TT) ? (t + 2) : (TT - 1);
        if constexpr (USEWS) {
            xL = *(const short8*)(xsb + (size_t)tn * DD + xlane);
        } else {
            xLa = *(const floatx4*)(xfb + (size_t)tn * DD + xlane);
            xLb = *(const floatx4*)(xfb + (size_t)tn * DD + xlane + 4);
        }

        // EW(t): pack one (b,j) quad per lane via register selects
        float g4[4];
        #pragma unroll
        for (int tg = 0; tg < 4; ++tg) {
            const float v01 = sb0 ? accP[tg][1] : accP[tg][0];
            const float v23 = sb0 ? accP[tg][3] : accP[tg][2];
            g4[tg] = sb1 ? v23 : v01;
        }
        const float iv = sig2(g4[0]);
        const float fv = sig2(g4[1]);
        const float gv = tanh2(g4[2]);
        const float ov = sig2(g4[3]);
        cval = fv * cval + iv * gv;
        hval = ov * tanh2(cval * (2.0f * LOG2E));

        unsigned hp;
        asm("v_cvt_pk_bf16_f32 %0, %1, %2" : "=v"(hp) : "v"(hval), "v"(hval));
        *(unsigned short*)((char*)h_lds + wro) = (unsigned short)hp;
        step_barrier();
    };

    #pragma unroll 1
    for (int t = 0; t < TT; t += 2) {
        // even step: read buf0, write buf1; accP=acc0, accN=acc1, xN=xf1
        STEP(acc0, acc1, xf1, xa1, xb1_, xf0, xa0, xb0_,
             rdA0, rdA1, rdA2, rdA3, wrB, t);
        // odd step: read buf1, write buf0; roles swap
        STEP(acc1, acc0, xf0, xa0, xb0_, xf1, xa1, xb1_,
             rdB0, rdB1, rdB2, rdB3, wrA, t + 1);
    }

    // ---- epilogue: h_n, c_n, q = h @ fc_w^T + fc_b ----
    {
        const long bg = (long)blockIdx.x * 4 + bp;
        out[10240 + bg * HH + jp]          = hval;   // h_n
        out[10240 + 131072 + bg * HH + jp] = cval;   // c_n
        hq[bp][jp] = hval;
    }
    __syncthreads();
    if (tid < 4 * AA) {
        const int b = tid / AA, a = tid - AA * b;
        float s = fc_b[a];
        const float* fw = fc_w + a * HH;
        const float* hr = &hq[b][0];
        #pragma unroll 8
        for (int j = 0; j < HH; ++j) s = fmaf(hr[j], fw[j], s);
        out[((long)blockIdx.x * 4 + b) * AA + a] = s;
    }
}

extern "C" void kernel_launch(void* const* d_in, const int* in_sizes, int n_in,
                              void* d_out, int out_size, void* d_ws, size_t ws_size,
                              hipStream_t stream) {
    const float* x    = (const float*)d_in[0];
    const float* W_ih = (const float*)d_in[1];
    const float* W_hh = (const float*)d_in[2];
    const float* b_ih = (const float*)d_in[3];
    const float* b_hh = (const float*)d_in[4];
    const float* fc_w = (const float*)d_in[5];
    const float* fc_b = (const float*)d_in[6];
    float* out = (float*)d_out;

    const size_t xelems = (size_t)1024 * TT * DD;       // 16.78M
    if (ws_size >= xelems * sizeof(unsigned short)) {
        unsigned short* xb = (unsigned short*)d_ws;
        xcvt<<<dim3(8192), dim3(256), 0, stream>>>(x, xb);
        lstm_fused<1><<<dim3(256), dim3(512), 0, stream>>>(
            x, xb, W_ih, W_hh, b_ih, b_hh, fc_w, fc_b, out);
    } else {
        lstm_fused<0><<<dim3(256), dim3(512), 0, stream>>>(
            x, nullptr, W_ih, W_hh, b_ih, b_hh, fc_w, fc_b, out);
    }
}

// Round 12
// 279.412 us; speedup vs baseline: 1.9224x; 1.0536x over previous
//
#include <hip/hip_runtime.h>

typedef short  short8  __attribute__((ext_vector_type(8)));
typedef float  floatx4 __attribute__((ext_vector_type(4)));

#define TT 512
#define DD 32
#define HH 128
#define AA 10
#define LOG2E 1.44269504088896340736f

__device__ __forceinline__ unsigned f2bf(float f) {
    unsigned u = __builtin_bit_cast(unsigned, f);
    return (u + 0x7fffu + ((u >> 16) & 1u)) >> 16;   // RNE f32 -> bf16
}

__device__ __forceinline__ short8 cvt8(floatx4 a, floatx4 b) {
    short8 r;
    r[0] = (short)f2bf(a[0]); r[1] = (short)f2bf(a[1]);
    r[2] = (short)f2bf(a[2]); r[3] = (short)f2bf(a[3]);
    r[4] = (short)f2bf(b[0]); r[5] = (short)f2bf(b[1]);
    r[6] = (short)f2bf(b[2]); r[7] = (short)f2bf(b[3]);
    return r;
}

// activations on pre-scaled gates (scale folded into weights/bias)
__device__ __forceinline__ float sig2(float a) {   // a = -x*log2e
    return __builtin_amdgcn_rcpf(1.0f + __builtin_amdgcn_exp2f(a));
}
__device__ __forceinline__ float tanh2(float a) {  // a = 2x*log2e
    return 1.0f - 2.0f * __builtin_amdgcn_rcpf(1.0f + __builtin_amdgcn_exp2f(a));
}

// lgkm-only step barrier: x prefetch loads float across it
__device__ __forceinline__ void step_barrier() {
    asm volatile("s_waitcnt lgkmcnt(0)" ::: "memory");
    __builtin_amdgcn_s_barrier();
    asm volatile("" ::: "memory");
}

// Prepass: x (f32) -> bf16 in d_ws, same [B][T][D] layout.
__global__ __launch_bounds__(256)
void xcvt(const float* __restrict__ x, unsigned short* __restrict__ xb) {
    const long i = (long)blockIdx.x * 256 + threadIdx.x;
    floatx4 a = *(const floatx4*)(x + 8 * i);
    floatx4 b = *(const floatx4*)(x + 8 * i + 4);
    *(short8*)(xb + 8 * i) = cvt8(a, b);
}

// One block = 4 batch rows; 256 blocks = 1 per CU.
// NEW vs R11: gate-ordered MFMA chains + split elementwise interleave.
// Program order per step (in-order issue => overlap structure):
//   [4 x-MFMAs next-step]      -- fills the ~120cy ds_read latency window
//   [i-chain x4][f-chain x4]
//   EW-A: iv, fv, t1 = fv*c    -- trans latency hides under g/o pipe time
//   [g-chain x4][o-chain x4]
//   EW-B: gv, c = fma(iv,gv,t1)
//   EW-C: ov, h, cvt_pk, ds_write, barrier   -- only this is hard-serial
// sched_barrier(0) after EW-A / EW-B pins the split against the compiler's
// MFMA re-clustering.  h layout: addr(b,j) = b*256 + ((2j+32b)&255).
template<int USEWS>
__global__ __launch_bounds__(512, 2)
void lstm_fused(const float* __restrict__ x,    const unsigned short* __restrict__ xbf,
                const float* __restrict__ W_ih, const float* __restrict__ W_hh,
                const float* __restrict__ b_ih, const float* __restrict__ b_hh,
                const float* __restrict__ fc_w, const float* __restrict__ fc_b,
                float* __restrict__ out)
{
    __shared__ unsigned short h_lds[2][4 * HH];    // 2 KiB total, dbuf
    __shared__ float hq[4][HH + 4];

    const int tid  = threadIdx.x;
    const int lane = tid & 63;
    const int w    = tid >> 6;
    const int l15  = lane & 15;
    const int lgrp = lane >> 4;     // k-group 0..3
    const int bloc = l15 & 3;       // batch row of this lane's B-frag

    // ---- resident A-fragments (bf16, gate-scaled) + bias C-operands ----
    short8  afr[4][5];
    floatx4 biasv[4];
    #pragma unroll
    for (int tg = 0; tg < 4; ++tg) {
        const float sc = (tg == 2) ? (2.0f * LOG2E) : (-LOG2E);
        const int m  = w + 8 * tg;
        const int ga = 16 * m + l15;
        #pragma unroll
        for (int s = 0; s < 4; ++s) {
            const float* p = W_hh + ga * HH + 32 * s + 8 * lgrp;
            afr[tg][s] = cvt8(*(const floatx4*)p * sc, *(const floatx4*)(p + 4) * sc);
        }
        {
            const float* p = W_ih + ga * DD + 8 * lgrp;
            afr[tg][4] = cvt8(*(const floatx4*)p * sc, *(const floatx4*)(p + 4) * sc);
        }
        #pragma unroll
        for (int r = 0; r < 4; ++r) {
            const int gd = 16 * m + 4 * lgrp + r;
            biasv[tg][r] = (b_ih[gd] + b_hh[gd]) * sc;
        }
    }

    // zero both h buffers: exactly 512 dwords
    ((unsigned*)h_lds)[tid] = 0u;
    __syncthreads();

    // packed-lane mapping: quad element rs = l15>>2
    const int rs  = l15 >> 2;
    const bool sb0 = (rs & 1) != 0;
    const bool sb1 = (rs & 2) != 0;
    const int bp  = bloc;
    const int jp  = 16 * w + 4 * lgrp + rs;

    // hoisted LDS offsets (rotation swizzle)
    const int rb = bloc * 256;
    const int rdA0 = rb + ((  0 + 16 * lgrp + 32 * bloc) & 255);
    const int rdA1 = rb + (( 64 + 16 * lgrp + 32 * bloc) & 255);
    const int rdA2 = rb + ((128 + 16 * lgrp + 32 * bloc) & 255);
    const int rdA3 = rb + ((192 + 16 * lgrp + 32 * bloc) & 255);
    const int rdB0 = rdA0 + 1024, rdB1 = rdA1 + 1024, rdB2 = rdA2 + 1024, rdB3 = rdA3 + 1024;
    const int wrA = bp * 256 + ((2 * jp + 32 * bp) & 255);          // write buf0
    const int wrB = wrA + 1024;                                      // write buf1

    // x addressing: scalar base walks with t (uniform), lane offset invariant
    const size_t blkbase = (size_t)blockIdx.x * 4 * TT * DD;
    const int    xlane   = bloc * (TT * DD) + 8 * lgrp;    // elements
    const unsigned short* xsb = xbf + blkbase;             // USEWS base
    const float*          xfb = x   + blkbase;             // fallback base

    // ---- prologue: acc0 = bias + W_ih@x(0); xf1 = x(1) ----
    floatx4 acc0[4], acc1[4];
    short8  xf0, xf1;
    floatx4 xa0, xb0_, xa1, xb1_;
    if constexpr (USEWS) {
        short8 xc0 = *(const short8*)(xsb + xlane);               // x(0)
        #pragma unroll
        for (int tg = 0; tg < 4; ++tg)
            acc0[tg] = __builtin_amdgcn_mfma_f32_16x16x32_bf16(afr[tg][4], xc0, biasv[tg], 0, 0, 0);
        xf1 = *(const short8*)(xsb + DD + xlane);                 // x(1)
    } else {
        floatx4 a0 = *(const floatx4*)(xfb + xlane);
        floatx4 b0 = *(const floatx4*)(xfb + xlane + 4);
        short8 xc0 = cvt8(a0, b0);
        #pragma unroll
        for (int tg = 0; tg < 4; ++tg)
            acc0[tg] = __builtin_amdgcn_mfma_f32_16x16x32_bf16(afr[tg][4], xc0, biasv[tg], 0, 0, 0);
        xa1  = *(const floatx4*)(xfb + DD + xlane);
        xb1_ = *(const floatx4*)(xfb + DD + xlane + 4);
    }

    float cval = 0.f, hval = 0.f;
    const char* lb = (const char*)h_lds;

    // STEP(t): see schedule in the kernel comment.
    auto STEP = [&](floatx4 (&accP)[4], floatx4 (&accN)[4],
                    short8& xN, floatx4& xNa, floatx4& xNb,
                    short8& xL, floatx4& xLa, floatx4& xLb,
                    int r0, int r1, int r2, int r3, int wro, int t) {
        // h fragment reads (latency covered by the x-MFMAs below)
        short8 hb0 = *(const short8*)(lb + r0);
        short8 hb1 = *(const short8*)(lb + r1);
        short8 hb2 = *(const short8*)(lb + r2);
        short8 hb3 = *(const short8*)(lb + r3);

        // 4 x-MFMAs for NEXT step (no LDS dependency -> issue first)
        short8 xc;
        if constexpr (USEWS) xc = xN; else xc = cvt8(xNa, xNb);
        #pragma unroll
        for (int tg = 0; tg < 4; ++tg)
            accN[tg] = __builtin_amdgcn_mfma_f32_16x16x32_bf16(afr[tg][4], xc, biasv[tg], 0, 0, 0);

        // prefetch x(t+2) (floats across the barrier)
        const int tn = (t + 2 < TT) ? (t + 2) : (TT - 1);
        if constexpr (USEWS) {
            xL = *(const short8*)(xsb + (size_t)tn * DD + xlane);
        } else {
            xLa = *(const floatx4*)(xfb + (size_t)tn * DD + xlane);
            xLb = *(const floatx4*)(xfb + (size_t)tn * DD + xlane + 4);
        }

        // gate i chain (tg=0), gate f chain (tg=1)
        accP[0] = __builtin_amdgcn_mfma_f32_16x16x32_bf16(afr[0][0], hb0, accP[0], 0, 0, 0);
        accP[0] = __builtin_amdgcn_mfma_f32_16x16x32_bf16(afr[0][1], hb1, accP[0], 0, 0, 0);
        accP[0] = __builtin_amdgcn_mfma_f32_16x16x32_bf16(afr[0][2], hb2, accP[0], 0, 0, 0);
        accP[0] = __builtin_amdgcn_mfma_f32_16x16x32_bf16(afr[0][3], hb3, accP[0], 0, 0, 0);
        accP[1] = __builtin_amdgcn_mfma_f32_16x16x32_bf16(afr[1][0], hb0, accP[1], 0, 0, 0);
        accP[1] = __builtin_amdgcn_mfma_f32_16x16x32_bf16(afr[1][1], hb1, accP[1], 0, 0, 0);
        accP[1] = __builtin_amdgcn_mfma_f32_16x16x32_bf16(afr[1][2], hb2, accP[1], 0, 0, 0);
        accP[1] = __builtin_amdgcn_mfma_f32_16x16x32_bf16(afr[1][3], hb3, accP[1], 0, 0, 0);

        // EW-A: iv, fv, t1 (trans latency hides under the g/o chains)
        float iv, fv, t1;
        {
            const float v01 = sb0 ? accP[0][1] : accP[0][0];
            const float v23 = sb0 ? accP[0][3] : accP[0][2];
            const float gi  = sb1 ? v23 : v01;
            const float u01 = sb0 ? accP[1][1] : accP[1][0];
            const float u23 = sb0 ? accP[1][3] : accP[1][2];
            const float gf  = sb1 ? u23 : u01;
            iv = sig2(gi);
            fv = sig2(gf);
            t1 = fv * cval;
        }
        __builtin_amdgcn_sched_barrier(0);

        // gate g chain (tg=2), gate o chain (tg=3)
        accP[2] = __builtin_amdgcn_mfma_f32_16x16x32_bf16(afr[2][0], hb0, accP[2], 0, 0, 0);
        accP[2] = __builtin_amdgcn_mfma_f32_16x16x32_bf16(afr[2][1], hb1, accP[2], 0, 0, 0);
        accP[2] = __builtin_amdgcn_mfma_f32_16x16x32_bf16(afr[2][2], hb2, accP[2], 0, 0, 0);
        accP[2] = __builtin_amdgcn_mfma_f32_16x16x32_bf16(afr[2][3], hb3, accP[2], 0, 0, 0);
        accP[3] = __builtin_amdgcn_mfma_f32_16x16x32_bf16(afr[3][0], hb0, accP[3], 0, 0, 0);
        accP[3] = __builtin_amdgcn_mfma_f32_16x16x32_bf16(afr[3][1], hb1, accP[3], 0, 0, 0);
        accP[3] = __builtin_amdgcn_mfma_f32_16x16x32_bf16(afr[3][2], hb2, accP[3], 0, 0, 0);
        accP[3] = __builtin_amdgcn_mfma_f32_16x16x32_bf16(afr[3][3], hb3, accP[3], 0, 0, 0);

        // EW-B: gv, cval (o-chain already in the pipe)
        {
            const float v01 = sb0 ? accP[2][1] : accP[2][0];
            const float v23 = sb0 ? accP[2][3] : accP[2][2];
            const float gg  = sb1 ? v23 : v01;
            const float gv  = tanh2(gg);
            cval = fmaf(iv, gv, t1);
        }
        __builtin_amdgcn_sched_barrier(0);

        // EW-C: ov, hval, write
        {
            const float v01 = sb0 ? accP[3][1] : accP[3][0];
            const float v23 = sb0 ? accP[3][3] : accP[3][2];
            const float go  = sb1 ? v23 : v01;
            const float ov  = sig2(go);
            hval = ov * tanh2(cval * (2.0f * LOG2E));
        }
        unsigned hp;
        asm("v_cvt_pk_bf16_f32 %0, %1, %2" : "=v"(hp) : "v"(hval), "v"(hval));
        *(unsigned short*)((char*)h_lds + wro) = (unsigned short)hp;
        step_barrier();
    };

    #pragma unroll 1
    for (int t = 0; t < TT; t += 2) {
        STEP(acc0, acc1, xf1, xa1, xb1_, xf0, xa0, xb0_,
             rdA0, rdA1, rdA2, rdA3, wrB, t);
        STEP(acc1, acc0, xf0, xa0, xb0_, xf1, xa1, xb1_,
             rdB0, rdB1, rdB2, rdB3, wrA, t + 1);
    }

    // ---- epilogue: h_n, c_n, q = h @ fc_w^T + fc_b ----
    {
        const long bg = (long)blockIdx.x * 4 + bp;
        out[10240 + bg * HH + jp]          = hval;   // h_n
        out[10240 + 131072 + bg * HH + jp] = cval;   // c_n
        hq[bp][jp] = hval;
    }
    __syncthreads();
    if (tid < 4 * AA) {
        const int b = tid / AA, a = tid - AA * b;
        float s = fc_b[a];
        const float* fw = fc_w + a * HH;
        const float* hr = &hq[b][0];
        #pragma unroll 8
        for (int j = 0; j < HH; ++j) s = fmaf(hr[j], fw[j], s);
        out[((long)blockIdx.x * 4 + b) * AA + a] = s;
    }
}

extern "C" void kernel_launch(void* const* d_in, const int* in_sizes, int n_in,
                              void* d_out, int out_size, void* d_ws, size_t ws_size,
                              hipStream_t stream) {
    const float* x    = (const float*)d_in[0];
    const float* W_ih = (const float*)d_in[1];
    const float* W_hh = (const float*)d_in[2];
    const float* b_ih = (const float*)d_in[3];
    const float* b_hh = (const float*)d_in[4];
    const float* fc_w = (const float*)d_in[5];
    const float* fc_b = (const float*)d_in[6];
    float* out = (float*)d_out;

    const size_t xelems = (size_t)1024 * TT * DD;       // 16.78M
    if (ws_size >= xelems * sizeof(unsigned short)) {
        unsigned short* xb = (unsigned short*)d_ws;
        xcvt<<<dim3(8192), dim3(256), 0, stream>>>(x, xb);
        lstm_fused<1><<<dim3(256), dim3(512), 0, stream>>>(
            x, xb, W_ih, W_hh, b_ih, b_hh, fc_w, fc_b, out);
    } else {
        lstm_fused<0><<<dim3(256), dim3(512), 0, stream>>>(
            x, nullptr, W_ih, W_hh, b_ih, b_hh, fc_w, fc_b, out);
    }
}